// Round 1
// baseline (232.362 us; speedup 1.0000x reference)
//
#include <hip/hip_runtime.h>
#include <hip/hip_bf16.h>
#include <math.h>

#define NB 8
#define NL 128
#define IND 512
#define OUTD 512
#define DEPN 45
#define DEPD 16
#define W1COLS (IND + DEPD)   // 528

// ---------------- K0: position-aware weights w[b,l] ----------------
__global__ void k0_posw(const unsigned char* mask_u8, float* wpos) {
    int b = blockIdx.x;           // 8 blocks
    int tid = threadIdx.x;        // 128 threads
    __shared__ int sflag, smin, smax;
    if (tid == 0) { sflag = 0; smin = NL; smax = -1; }
    __syncthreads();
    // Detect bool storage layout: numpy bool (1 byte) vs int32.
    // Read first 1024 bytes as 256 ints (safe in both layouts).
    const int* mi = (const int*)mask_u8;
    int v0 = mi[tid];
    int v1 = mi[tid + 128];
    if ((unsigned)v0 > 1u || (unsigned)v1 > 1u) atomicOr(&sflag, 1);
    __syncthreads();
    int isU8 = sflag;
    int mval;
    if (isU8) mval = (int)mask_u8[b * NL + tid];
    else      mval = mi[b * NL + tid];
    if (mval) { atomicMin(&smin, tid); atomicMax(&smax, tid); }
    __syncthreads();
    int any = (smax >= 0);
    int s = any ? smin : 0;
    int e = any ? smax : (NL - 1);
    const float invL = 1.0f / (float)NL;
    float w;
    if (tid < s)      w = 1.0f - (float)(s - tid) * invL;
    else if (tid > e) w = 1.0f - (float)(tid - e) * invL;
    else              w = 0.0f;
    if (mval) w = 0.0f;
    wpos[b * NL + tid] = w;
}

// ---------------- K2: Y1,Y2 (45x512), E[t] = Y1[t]·Y2[t] ----------------
__global__ void k2_y(const float* emb, const float* W1, const float* W2,
                     float* Y1, float* Y2, float* Ew) {
    int t = blockIdx.x;       // 45
    int o = threadIdx.x;      // 512
    float y1 = 0.f, y2 = 0.f;
#pragma unroll
    for (int e = 0; e < DEPD; e++) {
        float ev = emb[t * DEPD + e];
        y1 += ev * W1[o * W1COLS + IND + e];
        y2 += ev * W2[o * W1COLS + IND + e];
    }
    Y1[t * OUTD + o] = y1;
    Y2[t * OUTD + o] = y2;
    float p = y1 * y2;
    for (int off = 32; off; off >>= 1) p += __shfl_down(p, off, 64);
    __shared__ float red[8];
    int wid = o >> 6, lane = o & 63;
    if (lane == 0) red[wid] = p;
    __syncthreads();
    if (o == 0) {
        float s = 0.f;
        for (int i = 0; i < 8; i++) s += red[i];
        Ew[t] = s;
    }
}

// ---------------- KT: transpose W1h,W2h,Wg -> (d,o) layout ----------------
__global__ void kt_transpose(const float* W1, const float* W2, const float* Wg,
                             float* Wt1, float* Wt2, float* Wtg) {
    int idx = blockIdx.x * blockDim.x + threadIdx.x; // 512*512
    int d = idx >> 9, o = idx & 511;
    Wt1[idx] = W1[o * W1COLS + d];
    Wt2[idx] = W2[o * W1COLS + d];
    Wtg[idx] = Wg[o * IND + d];
}

// ---------------- K3: P1,P2,HT = h_pa @ {W1h,W2h,Wg}^T + b ----------------
__global__ __launch_bounds__(512) void k3_gemm(
    const float* __restrict__ h, const float* __restrict__ wpos,
    const float* __restrict__ Wt1, const float* __restrict__ Wt2,
    const float* __restrict__ Wtg,
    const float* __restrict__ b1, const float* __restrict__ b2,
    const float* __restrict__ bg,
    float* __restrict__ P1, float* __restrict__ P2, float* __restrict__ HT) {
    const int R = 8;
    int rowbase = blockIdx.x * R;   // 128 blocks
    int o = threadIdx.x;            // 512
    __shared__ float hs[R][IND];
#pragma unroll
    for (int r = 0; r < R; r++)
        hs[r][o] = h[(rowbase + r) * IND + o] * wpos[rowbase + r];
    __syncthreads();
    float a1[R], a2[R], ag[R];
#pragma unroll
    for (int r = 0; r < R; r++) { a1[r] = 0.f; a2[r] = 0.f; ag[r] = 0.f; }
    for (int d = 0; d < IND; d++) {
        float w1 = Wt1[d * OUTD + o];
        float w2 = Wt2[d * OUTD + o];
        float wg = Wtg[d * OUTD + o];
#pragma unroll
        for (int r = 0; r < R; r++) {
            float hv = hs[r][d];
            a1[r] += hv * w1;
            a2[r] += hv * w2;
            ag[r] += hv * wg;
        }
    }
    float bb1 = b1[o], bb2 = b2[o], bbg = bg[o];
#pragma unroll
    for (int r = 0; r < R; r++) {
        int row = rowbase + r;
        P1[row * OUTD + o] = a1[r] + bb1;
        P2[row * OUTD + o] = a2[r] + bb2;
        HT[row * OUTD + o] = ag[r] + bbg;
    }
}

// ---------------- K5: per-row scores + normalize + A@HT + relu ----------------
__global__ __launch_bounds__(256) void k5_out(
    const float* __restrict__ P1, const float* __restrict__ P2,
    const float* __restrict__ Y1, const float* __restrict__ Y2,
    const float* __restrict__ Ew, const int* __restrict__ dep,
    const float* __restrict__ HT, const float* __restrict__ bias,
    float* __restrict__ out) {
    int row = blockIdx.x;        // 1024
    int b = row >> 7, i = row & 127;
    int tid = threadIdx.x;       // 256
    __shared__ float ps1[512], ps2[512];
    __shared__ float pd1[DEPN][4], pd2[DEPN][4];
    __shared__ float comb[DEPN];
    __shared__ float a[NL];
    __shared__ float red[4];
    __shared__ float c0s, sumv;

    ps1[tid] = P1[row * 512 + tid];
    ps1[tid + 256] = P1[row * 512 + tid + 256];
    ps2[tid] = P2[row * 512 + tid];
    ps2[tid + 256] = P2[row * 512 + tid + 256];
    __syncthreads();

    // c0 = P1 · P2
    float lc = ps1[tid] * ps2[tid] + ps1[tid + 256] * ps2[tid + 256];
    for (int off = 32; off; off >>= 1) lc += __shfl_down(lc, off, 64);
    int wid = tid >> 6, lane = tid & 63;
    if (lane == 0) red[wid] = lc;
    __syncthreads();
    if (tid == 0) c0s = red[0] + red[1] + red[2] + red[3];

    // d1[t] = P1 · Y2[t],  d2[t] = Y1[t] · P2   (45 x 4-way split over o)
    if (tid < DEPN * 4) {
        int t = tid >> 2, q = tid & 3;
        const float* y1p = Y1 + t * 512 + q * 128;
        const float* y2p = Y2 + t * 512 + q * 128;
        const float* p1p = ps1 + q * 128;
        const float* p2p = ps2 + q * 128;
        float s1 = 0.f, s2 = 0.f;
        for (int o = 0; o < 128; o++) {
            s1 += p1p[o] * y2p[o];
            s2 += y1p[o] * p2p[o];
        }
        pd1[t][q] = s1;
        pd2[t][q] = s2;
    }
    __syncthreads();
    if (tid < DEPN) {
        comb[tid] = pd1[tid][0] + pd1[tid][1] + pd1[tid][2] + pd1[tid][3]
                  + pd2[tid][0] + pd2[tid][1] + pd2[tid][2] + pd2[tid][3]
                  + Ew[tid];
    }
    __syncthreads();

    float c0v = c0s;
    if (tid < NL) {
        int tt = dep[(b * NL + i) * NL + tid];
        float sc = 0.0f;
        if (tt != 0) sc = expf(c0v + comb[tt]);
        a[tid] = sc;
    }
    __syncthreads();
    if (tid < 64) {
        float v = a[tid] + a[tid + 64];
        for (int off = 32; off; off >>= 1) v += __shfl_down(v, off, 64);
        if (tid == 0) sumv = v;
    }
    __syncthreads();
    float inv = 1.0f / (sumv + 1e-6f);
    if (tid < NL) a[tid] *= inv;
    __syncthreads();

    // out[row, :] = relu(A_row @ HT[b] + bias)
    const float* htb = HT + b * NL * 512;
    float acc0 = bias[tid];
    float acc1 = bias[tid + 256];
#pragma unroll 4
    for (int j = 0; j < NL; j++) {
        float av = a[j];
        acc0 += av * htb[j * 512 + tid];
        acc1 += av * htb[j * 512 + tid + 256];
    }
    out[row * 512 + tid] = fmaxf(acc0, 0.0f);
    out[row * 512 + tid + 256] = fmaxf(acc1, 0.0f);
}

extern "C" void kernel_launch(void* const* d_in, const int* in_sizes, int n_in,
                              void* d_out, int out_size, void* d_ws, size_t ws_size,
                              hipStream_t stream) {
    const float* h    = (const float*)d_in[0];
    const int* dep    = (const int*)d_in[1];
    const unsigned char* mask = (const unsigned char*)d_in[2];
    const float* emb  = (const float*)d_in[3];
    const float* W1   = (const float*)d_in[4];
    const float* b1   = (const float*)d_in[5];
    const float* W2   = (const float*)d_in[6];
    const float* b2   = (const float*)d_in[7];
    const float* Wg   = (const float*)d_in[8];
    const float* bg   = (const float*)d_in[9];
    const float* bias = (const float*)d_in[10];
    float* out = (float*)d_out;

    float* ws = (float*)d_ws;
    float* wpos = ws;                 // 1024
    float* Y1   = wpos + 1024;        // 23040
    float* Y2   = Y1 + 23040;         // 23040
    float* Ew   = Y2 + 23040;         // 45 (pad 64)
    float* Wt1  = Ew + 64;            // 262144
    float* Wt2  = Wt1 + 262144;       // 262144
    float* Wtg  = Wt2 + 262144;       // 262144
    float* P1   = Wtg + 262144;       // 524288
    float* P2   = P1 + 524288;        // 524288
    float* HT   = P2 + 524288;        // 524288

    k0_posw<<<NB, NL, 0, stream>>>(mask, wpos);
    k2_y<<<DEPN, 512, 0, stream>>>(emb, W1, W2, Y1, Y2, Ew);
    kt_transpose<<<1024, 256, 0, stream>>>(W1, W2, Wg, Wt1, Wt2, Wtg);
    k3_gemm<<<NB * NL / 8, 512, 0, stream>>>(h, wpos, Wt1, Wt2, Wtg, b1, b2, bg, P1, P2, HT);
    k5_out<<<NB * NL, 256, 0, stream>>>(P1, P2, Y1, Y2, Ew, dep, HT, bias, out);
}

// Round 2
// 92.102 us; speedup vs baseline: 2.5229x; 2.5229x over previous
//
#include <hip/hip_runtime.h>
#include <hip/hip_bf16.h>
#include <math.h>

#define NB 8
#define NL 128
#define IND 512
#define OUTD 512
#define DEPN 45
#define DEPD 16
#define W1COLS (IND + DEPD)   // 528

// ---------------- K0: position-aware weights w[b,l] ----------------
__global__ void k0_posw(const unsigned char* mask_u8, float* wpos) {
    int b = blockIdx.x;           // 8 blocks
    int tid = threadIdx.x;        // 128 threads
    __shared__ int sflag, smin, smax;
    if (tid == 0) { sflag = 0; smin = NL; smax = -1; }
    __syncthreads();
    // Detect bool storage layout: numpy bool (1 byte) vs int32.
    const int* mi = (const int*)mask_u8;
    int v0 = mi[tid];
    int v1 = mi[tid + 128];
    if ((unsigned)v0 > 1u || (unsigned)v1 > 1u) atomicOr(&sflag, 1);
    __syncthreads();
    int isU8 = sflag;
    int mval;
    if (isU8) mval = (int)mask_u8[b * NL + tid];
    else      mval = mi[b * NL + tid];
    if (mval) { atomicMin(&smin, tid); atomicMax(&smax, tid); }
    __syncthreads();
    int any = (smax >= 0);
    int s = any ? smin : 0;
    int e = any ? smax : (NL - 1);
    const float invL = 1.0f / (float)NL;
    float w;
    if (tid < s)      w = 1.0f - (float)(s - tid) * invL;
    else if (tid > e) w = 1.0f - (float)(tid - e) * invL;
    else              w = 0.0f;
    if (mval) w = 0.0f;
    wpos[b * NL + tid] = w;
}

// ---------------- K2: Y1,Y2 (45x512), E[t] = Y1[t]·Y2[t] ----------------
__global__ void k2_y(const float* emb, const float* W1, const float* W2,
                     float* Y1, float* Y2, float* Ew) {
    int t = blockIdx.x;       // 45
    int o = threadIdx.x;      // 512
    float y1 = 0.f, y2 = 0.f;
#pragma unroll
    for (int e = 0; e < DEPD; e++) {
        float ev = emb[t * DEPD + e];
        y1 += ev * W1[o * W1COLS + IND + e];
        y2 += ev * W2[o * W1COLS + IND + e];
    }
    Y1[t * OUTD + o] = y1;
    Y2[t * OUTD + o] = y2;
    float p = y1 * y2;
    for (int off = 32; off; off >>= 1) p += __shfl_down(p, off, 64);
    __shared__ float red[8];
    int wid = o >> 6, lane = o & 63;
    if (lane == 0) red[wid] = p;
    __syncthreads();
    if (o == 0) {
        float s = 0.f;
        for (int i = 0; i < 8; i++) s += red[i];
        Ew[t] = s;
    }
}

// ---------------- KT: transpose W1h,W2h,Wg -> (d,o) layout ----------------
__global__ void kt_transpose(const float* W1, const float* W2, const float* Wg,
                             float* Wt1, float* Wt2, float* Wtg) {
    int idx = blockIdx.x * blockDim.x + threadIdx.x; // 512*512
    int d = idx >> 9, o = idx & 511;
    Wt1[idx] = W1[o * W1COLS + d];
    Wt2[idx] = W2[o * W1COLS + d];
    Wtg[idx] = Wg[o * IND + d];
}

// ---------------- K3: P{1,2},HT = h_pa @ {W1h,W2h,Wg}^T + b ----------------
// Register-tiled fp32 GEMM. Block = 16 rows x 128 cols x 1 matrix.
// 128 threads = 32 colthreads (4 cols each, float4) x 4 rowgroups (4 rows each).
// Grid = 64 rowgroups x 4 colchunks x 3 matrices = 768 blocks = 3 blocks/CU.
__global__ __launch_bounds__(128) void k3_gemm(
    const float* __restrict__ h, const float* __restrict__ wpos,
    const float* __restrict__ Wt,     // [3][512 d][512 o] contiguous
    const float* __restrict__ b1, const float* __restrict__ b2,
    const float* __restrict__ bg,
    float* __restrict__ Pout) {       // [3][1024][512] contiguous
    int rb = blockIdx.x * 16;         // row base
    int cb = blockIdx.y * 128;        // col base
    int m  = blockIdx.z;              // matrix
    int tid = threadIdx.x;
    int c = tid & 31;                 // colthread
    int g = tid >> 5;                 // rowgroup 0..3
    int col = cb + c * 4;
    const float* bb = (m == 0) ? b1 : (m == 1) ? b2 : bg;

    __shared__ float hs[16][IND];
    // stage 16 rows of h scaled by wpos (32 KB)
    for (int idx = tid; idx < 16 * 128; idx += 128) {
        int r = idx >> 7;             // 0..15
        int dc = (idx & 127) << 2;    // 0..508 step 4
        float4 hv = *(const float4*)&h[(size_t)(rb + r) * IND + dc];
        float wv = wpos[rb + r];
        hv.x *= wv; hv.y *= wv; hv.z *= wv; hv.w *= wv;
        *(float4*)&hs[r][dc] = hv;
    }
    __syncthreads();

    float acc[4][4];
#pragma unroll
    for (int r = 0; r < 4; r++)
#pragma unroll
        for (int q = 0; q < 4; q++) acc[r][q] = 0.f;

    const float* Wp = Wt + (size_t)m * IND * OUTD + col;
#pragma unroll 2
    for (int d = 0; d < IND; d += 4) {
        float4 w0 = *(const float4*)(Wp + (size_t)(d + 0) * OUTD);
        float4 w1 = *(const float4*)(Wp + (size_t)(d + 1) * OUTD);
        float4 w2 = *(const float4*)(Wp + (size_t)(d + 2) * OUTD);
        float4 w3 = *(const float4*)(Wp + (size_t)(d + 3) * OUTD);
#pragma unroll
        for (int r = 0; r < 4; r++) {
            float4 hv = *(const float4*)&hs[g * 4 + r][d];
            acc[r][0] += hv.x * w0.x + hv.y * w1.x + hv.z * w2.x + hv.w * w3.x;
            acc[r][1] += hv.x * w0.y + hv.y * w1.y + hv.z * w2.y + hv.w * w3.y;
            acc[r][2] += hv.x * w0.z + hv.y * w1.z + hv.z * w2.z + hv.w * w3.z;
            acc[r][3] += hv.x * w0.w + hv.y * w1.w + hv.z * w2.w + hv.w * w3.w;
        }
    }

    float4 bb4 = *(const float4*)&bb[col];
#pragma unroll
    for (int r = 0; r < 4; r++) {
        int row = rb + g * 4 + r;
        float4 o;
        o.x = acc[r][0] + bb4.x;
        o.y = acc[r][1] + bb4.y;
        o.z = acc[r][2] + bb4.z;
        o.w = acc[r][3] + bb4.w;
        *(float4*)&Pout[(size_t)m * 1024 * OUTD + (size_t)row * OUTD + col] = o;
    }
}

// ---------------- K5: per-row scores + normalize + A@HT + relu ----------------
__global__ __launch_bounds__(256) void k5_out(
    const float* __restrict__ P1, const float* __restrict__ P2,
    const float* __restrict__ Y1, const float* __restrict__ Y2,
    const float* __restrict__ Ew, const int* __restrict__ dep,
    const float* __restrict__ HT, const float* __restrict__ bias,
    float* __restrict__ out) {
    int row = blockIdx.x;        // 1024
    int b = row >> 7, i = row & 127;
    int tid = threadIdx.x;       // 256
    __shared__ float ps1[512], ps2[512];
    __shared__ float pd1[DEPN][4], pd2[DEPN][4];
    __shared__ float comb[DEPN];
    __shared__ float a[NL];
    __shared__ float red[4];
    __shared__ float c0s, sumv;

    ps1[tid] = P1[row * 512 + tid];
    ps1[tid + 256] = P1[row * 512 + tid + 256];
    ps2[tid] = P2[row * 512 + tid];
    ps2[tid + 256] = P2[row * 512 + tid + 256];
    __syncthreads();

    // c0 = P1 · P2
    float lc = ps1[tid] * ps2[tid] + ps1[tid + 256] * ps2[tid + 256];
    for (int off = 32; off; off >>= 1) lc += __shfl_down(lc, off, 64);
    int wid = tid >> 6, lane = tid & 63;
    if (lane == 0) red[wid] = lc;
    __syncthreads();
    if (tid == 0) c0s = red[0] + red[1] + red[2] + red[3];

    // d1[t] = P1 · Y2[t],  d2[t] = Y1[t] · P2   (45 x 4-way split over o)
    if (tid < DEPN * 4) {
        int t = tid >> 2, q = tid & 3;
        const float* y1p = Y1 + t * 512 + q * 128;
        const float* y2p = Y2 + t * 512 + q * 128;
        const float* p1p = ps1 + q * 128;
        const float* p2p = ps2 + q * 128;
        float s1 = 0.f, s2 = 0.f;
        for (int o = 0; o < 128; o++) {
            s1 += p1p[o] * y2p[o];
            s2 += y1p[o] * p2p[o];
        }
        pd1[t][q] = s1;
        pd2[t][q] = s2;
    }
    __syncthreads();
    if (tid < DEPN) {
        comb[tid] = pd1[tid][0] + pd1[tid][1] + pd1[tid][2] + pd1[tid][3]
                  + pd2[tid][0] + pd2[tid][1] + pd2[tid][2] + pd2[tid][3]
                  + Ew[tid];
    }
    __syncthreads();

    float c0v = c0s;
    if (tid < NL) {
        int tt = dep[(b * NL + i) * NL + tid];
        float sc = 0.0f;
        if (tt != 0) sc = expf(c0v + comb[tt]);
        a[tid] = sc;
    }
    __syncthreads();
    if (tid < 64) {
        float v = a[tid] + a[tid + 64];
        for (int off = 32; off; off >>= 1) v += __shfl_down(v, off, 64);
        if (tid == 0) sumv = v;
    }
    __syncthreads();
    float inv = 1.0f / (sumv + 1e-6f);
    if (tid < NL) a[tid] *= inv;
    __syncthreads();

    // out[row, :] = relu(A_row @ HT[b] + bias)
    const float* htb = HT + b * NL * 512;
    float acc0 = bias[tid];
    float acc1 = bias[tid + 256];
#pragma unroll 4
    for (int j = 0; j < NL; j++) {
        float av = a[j];
        acc0 += av * htb[j * 512 + tid];
        acc1 += av * htb[j * 512 + tid + 256];
    }
    out[row * 512 + tid] = fmaxf(acc0, 0.0f);
    out[row * 512 + tid + 256] = fmaxf(acc1, 0.0f);
}

extern "C" void kernel_launch(void* const* d_in, const int* in_sizes, int n_in,
                              void* d_out, int out_size, void* d_ws, size_t ws_size,
                              hipStream_t stream) {
    const float* h    = (const float*)d_in[0];
    const int* dep    = (const int*)d_in[1];
    const unsigned char* mask = (const unsigned char*)d_in[2];
    const float* emb  = (const float*)d_in[3];
    const float* W1   = (const float*)d_in[4];
    const float* b1   = (const float*)d_in[5];
    const float* W2   = (const float*)d_in[6];
    const float* b2   = (const float*)d_in[7];
    const float* Wg   = (const float*)d_in[8];
    const float* bg   = (const float*)d_in[9];
    const float* bias = (const float*)d_in[10];
    float* out = (float*)d_out;

    float* ws = (float*)d_ws;
    float* wpos = ws;                 // 1024
    float* Y1   = wpos + 1024;        // 23040
    float* Y2   = Y1 + 23040;         // 23040
    float* Ew   = Y2 + 23040;         // 45 (pad 64)
    float* Wt1  = Ew + 64;            // 262144  (Wt[3] contiguous from here)
    float* Wt2  = Wt1 + 262144;       // 262144
    float* Wtg  = Wt2 + 262144;       // 262144
    float* P1   = Wtg + 262144;       // 524288  (Pout[3] contiguous from here)
    float* P2   = P1 + 524288;        // 524288
    float* HT   = P2 + 524288;        // 524288

    k0_posw<<<NB, NL, 0, stream>>>(mask, wpos);
    k2_y<<<DEPN, 512, 0, stream>>>(emb, W1, W2, Y1, Y2, Ew);
    kt_transpose<<<1024, 256, 0, stream>>>(W1, W2, Wg, Wt1, Wt2, Wtg);
    dim3 g3(64, 4, 3);
    k3_gemm<<<g3, 128, 0, stream>>>(h, wpos, Wt1, b1, b2, bg, P1);
    k5_out<<<NB * NL, 256, 0, stream>>>(P1, P2, Y1, Y2, Ew, dep, HT, bias, out);
}